// Round 12
// baseline (1312.197 us; speedup 1.0000x reference)
//
#include <hip/hip_runtime.h>
#include <math.h>

#define NCC 64
#define NB 8
#define VOL (NCC*NCC*NCC)      // 262144 = 2^18
#define TOT (NB*VOL)           // 2097152
#define WTOT 170869            // total weight elements
#define PI2 6.2831853071795864769f
#define HS 287496              // 66*66*66 halo slots per batch elem
#define SX 4356                // 66*66

typedef unsigned short u16;
typedef __bf16 bf16x8 __attribute__((ext_vector_type(8)));
typedef float f32x16 __attribute__((ext_vector_type(16)));

__device__ __forceinline__ float b2f(u16 h){ return __uint_as_float(((unsigned)h)<<16); }
__device__ __forceinline__ u16 f2b(float f){
  unsigned u = __float_as_uint(f);
  unsigned r = (u + 0x7FFFu + ((u>>16)&1u)) >> 16;
  return (u16)r;
}
__device__ __forceinline__ float fsig(float x){ return 1.f / (1.f + __expf(-x)); }
__device__ __forceinline__ float ftanh(float x){
  float e = __expf(2.f * x);
  return 1.f - 2.f / (e + 1.f);
}

// ================= radix-8 FFT machinery =================
template<bool INV>
__device__ __forceinline__ void fft8(float2* x) {
  const float C = 0.70710678118654752440f;
  float2 s0,s1,s2,s3,s4,s5,s6,s7;
  s0 = make_float2(x[0].x + x[4].x, x[0].y + x[4].y);
  s4 = make_float2(x[0].x - x[4].x, x[0].y - x[4].y);
  s1 = make_float2(x[1].x + x[5].x, x[1].y + x[5].y);
  s5 = make_float2(x[1].x - x[5].x, x[1].y - x[5].y);
  s2 = make_float2(x[2].x + x[6].x, x[2].y + x[6].y);
  s6 = make_float2(x[2].x - x[6].x, x[2].y - x[6].y);
  s3 = make_float2(x[3].x + x[7].x, x[3].y + x[7].y);
  s7 = make_float2(x[3].x - x[7].x, x[3].y - x[7].y);
  float2 n5, n6, n7;
  if (!INV) {
    n5 = make_float2(C*(s5.x + s5.y), C*(s5.y - s5.x));
    n6 = make_float2(s6.y, -s6.x);
    n7 = make_float2(C*(s7.y - s7.x), -C*(s7.x + s7.y));
  } else {
    n5 = make_float2(C*(s5.x - s5.y), C*(s5.y + s5.x));
    n6 = make_float2(-s6.y, s6.x);
    n7 = make_float2(-C*(s7.x + s7.y), C*(s7.x - s7.y));
  }
  float2 t0,t1,t2,t3,t4,t5,t6,t7,d;
  t0 = make_float2(s0.x + s2.x, s0.y + s2.y);
  t2 = make_float2(s0.x - s2.x, s0.y - s2.y);
  t1 = make_float2(s1.x + s3.x, s1.y + s3.y);
  d  = make_float2(s1.x - s3.x, s1.y - s3.y);
  t3 = INV ? make_float2(-d.y, d.x) : make_float2(d.y, -d.x);
  t4 = make_float2(s4.x + n6.x, s4.y + n6.y);
  t6 = make_float2(s4.x - n6.x, s4.y - n6.y);
  t5 = make_float2(n5.x + n7.x, n5.y + n7.y);
  d  = make_float2(n5.x - n7.x, n5.y - n7.y);
  t7 = INV ? make_float2(-d.y, d.x) : make_float2(d.y, -d.x);
  x[0] = make_float2(t0.x + t1.x, t0.y + t1.y);
  x[1] = make_float2(t0.x - t1.x, t0.y - t1.y);
  x[2] = make_float2(t2.x + t3.x, t2.y + t3.y);
  x[3] = make_float2(t2.x - t3.x, t2.y - t3.y);
  x[4] = make_float2(t4.x + t5.x, t4.y + t5.y);
  x[5] = make_float2(t4.x - t5.x, t4.y - t5.y);
  x[6] = make_float2(t6.x + t7.x, t6.y + t7.y);
  x[7] = make_float2(t6.x - t7.x, t6.y - t7.y);
}

template<bool INV>
__device__ __forceinline__ void dft64(float2* Pf, const float2* tw, int ls, int ns) {
  const int BR[8] = {0,4,2,6,1,5,3,7};
  int t = threadIdx.x;
  int L0 = t >> 3, b = t & 7, L1 = L0 + 32;
  float2 v0[8], v1[8];
  #pragma unroll
  for (int a = 0; a < 8; ++a) v0[a] = Pf[L0*ls + (8*a + b)*ns];
  #pragma unroll
  for (int a = 0; a < 8; ++a) v1[a] = Pf[L1*ls + (8*a + b)*ns];
  __syncthreads();
  fft8<INV>(v0); fft8<INV>(v1);
  #pragma unroll
  for (int r = 0; r < 8; ++r) {
    float2 w = tw[(b * r) & 63];
    if (INV) w.y = -w.y;
    float2 a0 = v0[BR[r]], a1 = v1[BR[r]];
    Pf[L0*ls + (8*b + r)*ns] = make_float2(a0.x*w.x - a0.y*w.y, a0.x*w.y + a0.y*w.x);
    Pf[L1*ls + (8*b + r)*ns] = make_float2(a1.x*w.x - a1.y*w.y, a1.x*w.y + a1.y*w.x);
  }
  __syncthreads();
  int r = t & 7;
  #pragma unroll
  for (int q = 0; q < 8; ++q) v0[q] = Pf[L0*ls + (8*q + r)*ns];
  #pragma unroll
  for (int q = 0; q < 8; ++q) v1[q] = Pf[L1*ls + (8*q + r)*ns];
  fft8<INV>(v0); fft8<INV>(v1);
  #pragma unroll
  for (int j = 0; j < 8; ++j) {
    Pf[L0*ls + (8*BR[j] + r)*ns] = v0[j];
    Pf[L1*ls + (8*BR[j] + r)*ns] = v1[j];
  }
  __syncthreads();
}

// ================= setup kernels =================
__global__ __launch_bounds__(256) void k_sniff(const u16* __restrict__ x, int* __restrict__ flag) {
  __shared__ int cnt;
  if (threadIdx.x == 0) cnt = 0;
  __syncthreads();
  int sane = 0;
  for (int i = threadIdx.x; i < 1024; i += 256) {
    u16 h = x[2 * i];
    int e = (h >> 7) & 0xFF;
    if (h == 0 || (e >= 0x68 && e <= 0x8F)) sane++;
  }
  atomicAdd(&cnt, sane);
  __syncthreads();
  if (threadIdx.x == 0) flag[0] = (cnt >= 768) ? 1 : 0;
}

__global__ __launch_bounds__(256) void k_cvt(const void* __restrict__ in, size_t eoff,
                                             float* __restrict__ out, const int* __restrict__ flag) {
  size_t i = (size_t)blockIdx.x * 256 + threadIdx.x;
  if (*flag) out[i] = b2f(((const u16*)in)[eoff + i]);
  else       out[i] = ((const float*)in)[eoff + i];
}

__global__ __launch_bounds__(256) void k_cvtall(
    const void* s0, const void* s1, const void* s2, const void* s3,
    const void* s4, const void* s5, const void* s6, const void* s7,
    const void* s8, const void* s9, const void* s10, const void* s11,
    const void* s12, const void* s13, const void* s14, const void* s15,
    float* __restrict__ out, const int* __restrict__ flag) {
  const void* ps[16] = {s0,s1,s2,s3,s4,s5,s6,s7,s8,s9,s10,s11,s12,s13,s14,s15};
  const int offs[17] = {0,432,440,7352,14264,14296,14512,14513,30897,31025,
                        96561,162097,162609,170801,170865,170868,170869};
  int i = blockIdx.x * 256 + threadIdx.x;
  if (i >= WTOT) return;
  int s = 0;
  #pragma unroll
  for (int k = 1; k < 16; ++k) if (i >= offs[k]) s = k;
  int j = i - offs[s];
  if (*flag) out[i] = b2f(((const u16*)ps[s])[j]);
  else       out[i] = ((const float*)ps[s])[j];
}

// Wf[tap][hi][co][j] : u16 idx = tap*512 + hi*256 + co*8 + j
__global__ __launch_bounds__(256) void k_mkwf(const void* __restrict__ Wx, const void* __restrict__ Wh,
                                              const int* __restrict__ flag, u16* __restrict__ Wf) {
  int i = blockIdx.x * 256 + threadIdx.x;   // 13824
  if (i >= 13824) return;
  int j = i & 7, co = (i >> 3) & 31, hi = (i >> 8) & 1, tap = i >> 9;
  int src = tap * 256 + j * 32 + co;
  const void* P = hi ? Wh : Wx;
  u16 val;
  if (*flag) val = ((const u16*)P)[src];
  else       val = f2b(((const float*)P)[src]);
  Wf[i] = val;
}

// Wfo[p][hi][co][j]: only co==0 carries Wo[tap=2p+hi][j]; rest zero
__global__ __launch_bounds__(256) void k_mkwfo(const void* __restrict__ Wo,
                                               const int* __restrict__ flag, u16* __restrict__ Wfo) {
  int i = blockIdx.x * 256 + threadIdx.x;   // 7168 = 14*512
  if (i >= 7168) return;
  int j = i & 7, co = (i >> 3) & 31, hi = (i >> 8) & 1, p = i >> 9;
  int tap = 2 * p + hi;
  u16 val = 0;
  if (co == 0 && tap < 27) {
    int src = tap * 8 + j;
    val = *flag ? ((const u16*)Wo)[src] : f2b(((const float*)Wo)[src]);
  }
  Wfo[i] = val;
}

// Wfi[m][hi][co][j]: A[row=co][k=hi*8+j] for cellin MFMA; k -> (tap = m*8 + (k>>1), ch = k&1)
// value = Win[tap*16 + ch*8 + co] when co<8 && tap<27, else 0
__global__ __launch_bounds__(256) void k_mkwfi(const void* __restrict__ Wi,
                                               const int* __restrict__ flag, u16* __restrict__ Wfi) {
  int i = blockIdx.x * 256 + threadIdx.x;   // 2048 = 4*512
  if (i >= 2048) return;
  int j = i & 7, co = (i >> 3) & 31, hi = (i >> 8) & 1, m = i >> 9;
  int k = hi * 8 + j;
  int tap = m * 8 + (k >> 1), ch = k & 1;
  u16 val = 0;
  if (co < 8 && tap < 27) {
    int src = tap * 16 + ch * 8 + co;
    val = *flag ? ((const u16*)Wi)[src] : f2b(((const float*)Wi)[src]);
  }
  Wfi[i] = val;
}

__global__ __launch_bounds__(256) void k_counts(const int* __restrict__ kbin,
                                                float* __restrict__ cnts) {
  __shared__ float s[NCC];
  int t = threadIdx.x;
  if (t < NCC) s[t] = 0.f;
  __syncthreads();
  int i = blockIdx.x * 256 + t;
  atomicAdd(&s[kbin[i]], 1.f);
  __syncthreads();
  if (t < NCC) atomicAdd(&cnts[t], s[t]);
}

// ================= FFT kernels =================
__global__ __launch_bounds__(256) void k_fft_zy_adam(
    const float* __restrict__ pos, const void* __restrict__ yraw, size_t yoff,
    float* __restrict__ m, float* __restrict__ v, float* __restrict__ dpw,
    float2* __restrict__ cout, float ib1, float ib2, int first,
    const int* __restrict__ flag, float* __restrict__ psp, float* __restrict__ psd) {
  __shared__ float2 P[64*66];
  __shared__ float2 tw[64];
  int t = threadIdx.x;
  if (t < 64) { float s, c; __sincosf(-(PI2/64.f)*(float)t, &s, &c); tw[t] = make_float2(c, s); }
  int bb = blockIdx.x >> 6, xx = blockIdx.x & 63;
  if (xx == 0) {
    if (t < 64)                 psp[bb*64 + t] = 0.f;
    else if (t < 128)           psd[bb*64 + (t - 64)] = 0.f;
  }
  size_t pb = (size_t)blockIdx.x * 4096;
  int bf = *flag;
  #pragma unroll
  for (int i = 0; i < 4; ++i) {
    int i4 = t + 256*i;
    float4 p4 = ((const float4*)(pos + pb))[i4];
    float yv[4];
    if (bf) {
      uint2 yu = ((const uint2*)((const u16*)yraw + yoff + pb))[i4];
      const u16* yp = (const u16*)&yu;
      yv[0]=b2f(yp[0]); yv[1]=b2f(yp[1]); yv[2]=b2f(yp[2]); yv[3]=b2f(yp[3]);
    } else {
      float4 y4 = ((const float4*)((const float*)yraw + yoff + pb))[i4];
      yv[0]=y4.x; yv[1]=y4.y; yv[2]=y4.z; yv[3]=y4.w;
    }
    float pv[4] = {p4.x, p4.y, p4.z, p4.w};
    float mo[4], vo[4], dd[4];
    if (!first) {
      float4 m4 = ((const float4*)(m + pb))[i4];
      float4 v4 = ((const float4*)(v + pb))[i4];
      mo[0]=m4.x; mo[1]=m4.y; mo[2]=m4.z; mo[3]=m4.w;
      vo[0]=v4.x; vo[1]=v4.y; vo[2]=v4.z; vo[3]=v4.w;
    }
    #pragma unroll
    for (int c = 0; c < 4; ++c) {
      float g = pv[c] - yv[c];
      float mi = first ? 0.1f*g : 0.9f*mo[c] + 0.1f*g;
      float vi = first ? 0.001f*g*g : 0.999f*vo[c] + 0.001f*g*g;
      mo[c] = mi; vo[c] = vi;
      dd[c] = -0.1f * (mi * ib1) / (sqrtf(vi * ib2) + 1e-7f);
    }
    ((float4*)(m + pb))[i4]   = make_float4(mo[0], mo[1], mo[2], mo[3]);
    ((float4*)(v + pb))[i4]   = make_float4(vo[0], vo[1], vo[2], vo[3]);
    ((float4*)(dpw + pb))[i4] = make_float4(dd[0], dd[1], dd[2], dd[3]);
    int base = i4 * 4;
    float2* row = P + (base >> 6)*66 + (base & 63);
    row[0] = make_float2(pv[0], 0.f);
    row[1] = make_float2(pv[1], 0.f);
    row[2] = make_float2(pv[2], 0.f);
    row[3] = make_float2(pv[3], 0.f);
  }
  __syncthreads();
  dft64<false>(P, tw, 66, 1);
  dft64<false>(P, tw, 1, 66);
  float4* dst = (float4*)(cout + pb);
  #pragma unroll
  for (int i = 0; i < 8; ++i) {
    int idx2 = (t + 256*i) * 2;
    float2 a = P[(idx2 >> 6)*66 + (idx2 & 63)];
    float2 b = P[(idx2 >> 6)*66 + (idx2 & 63) + 1];
    dst[t + 256*i] = make_float4(a.x, a.y, b.x, b.y);
  }
}

__global__ __launch_bounds__(256) void k_fft_zy(const float* __restrict__ rin,
                                                float2* __restrict__ cout) {
  __shared__ float2 P[64*66];
  __shared__ float2 tw[64];
  int t = threadIdx.x;
  if (t < 64) { float s, c; __sincosf(-(PI2/64.f)*(float)t, &s, &c); tw[t] = make_float2(c, s); }
  const float* src = rin + (size_t)blockIdx.x * 4096;
  #pragma unroll
  for (int i = 0; i < 4; ++i) {
    float4 v = ((const float4*)src)[t + 256*i];
    int base = (t + 256*i) * 4;
    float2* row = P + (base >> 6)*66 + (base & 63);
    row[0] = make_float2(v.x, 0.f);
    row[1] = make_float2(v.y, 0.f);
    row[2] = make_float2(v.z, 0.f);
    row[3] = make_float2(v.w, 0.f);
  }
  __syncthreads();
  dft64<false>(P, tw, 66, 1);
  dft64<false>(P, tw, 1, 66);
  float4* dst = (float4*)(cout + (size_t)blockIdx.x * 4096);
  #pragma unroll
  for (int i = 0; i < 8; ++i) {
    int idx2 = (t + 256*i) * 2;
    float2 a = P[(idx2 >> 6)*66 + (idx2 & 63)];
    float2 b = P[(idx2 >> 6)*66 + (idx2 & 63) + 1];
    dst[t + 256*i] = make_float4(a.x, a.y, b.x, b.y);
  }
}

__global__ __launch_bounds__(256) void k_fft_x_pow(const float2* __restrict__ cin,
                                                   const int* __restrict__ kb,
                                                   float* __restrict__ psum) {
  __shared__ float2 P[64*66];
  __shared__ float2 tw[64];
  __shared__ float pb[64];
  int t = threadIdx.x;
  if (t < 64) { float s, c; __sincosf(-(PI2/64.f)*(float)t, &s, &c); tw[t] = make_float2(c, s); pb[t] = 0.f; }
  int b = blockIdx.x >> 6, y = blockIdx.x & 63;
  #pragma unroll
  for (int i = 0; i < 8; ++i) {
    int idx2 = (t + 256*i) * 2;
    int x = idx2 >> 6, z = idx2 & 63;
    float4 v = *(const float4*)(cin + (((size_t)(b*64 + x)*64 + y)*64 + z));
    P[x*66 + z]     = make_float2(v.x, v.y);
    P[x*66 + z + 1] = make_float2(v.z, v.w);
  }
  __syncthreads();
  dft64<false>(P, tw, 1, 66);
  const float INV2 = 1.0f / ((float)VOL * (float)VOL);
  #pragma unroll
  for (int i = 0; i < 16; ++i) {
    int idx = t + 256*i;
    int x = idx >> 6, z = idx & 63;
    float2 a = P[x*66 + z];
    float pm = (a.x*a.x + a.y*a.y) * INV2;
    atomicAdd(&pb[kb[(x*64 + y)*64 + z]], pm);
  }
  __syncthreads();
  if (t < 64) atomicAdd(&psum[b*64 + t], pb[t]);
}

__global__ __launch_bounds__(256) void k_fft_x_filt(float2* __restrict__ cb,
                                                    const int* __restrict__ kb,
                                                    const float* __restrict__ psn) {
  __shared__ float2 P[64*66];
  __shared__ float2 tw[64];
  int t = threadIdx.x;
  if (t < 64) { float s, c; __sincosf(-(PI2/64.f)*(float)t, &s, &c); tw[t] = make_float2(c, s); }
  int b = blockIdx.x >> 6, y = blockIdx.x & 63;
  #pragma unroll
  for (int i = 0; i < 8; ++i) {
    int idx2 = (t + 256*i) * 2;
    int x = idx2 >> 6, z = idx2 & 63;
    float4 v = *(const float4*)(cb + (((size_t)(b*64 + x)*64 + y)*64 + z));
    P[x*66 + z]     = make_float2(v.x, v.y);
    P[x*66 + z + 1] = make_float2(v.z, v.w);
  }
  __syncthreads();
  dft64<false>(P, tw, 1, 66);
  #pragma unroll
  for (int i = 0; i < 16; ++i) {
    int idx = t + 256*i;
    int x = idx >> 6, z = idx & 63;
    float fac = sqrtf(psn[b*64 + kb[(x*64 + y)*64 + z]]);
    float2 a = P[x*66 + z];
    P[x*66 + z] = make_float2(a.x * fac, a.y * fac);
  }
  __syncthreads();
  dft64<true>(P, tw, 1, 66);
  #pragma unroll
  for (int i = 0; i < 8; ++i) {
    int idx2 = (t + 256*i) * 2;
    int x = idx2 >> 6, z = idx2 & 63;
    float2 a = P[x*66 + z], c = P[x*66 + z + 1];
    *(float4*)(cb + (((size_t)(b*64 + x)*64 + y)*64 + z)) = make_float4(a.x, a.y, c.x, c.y);
  }
}

// inverse y,z + pos update + loss; optionally writes final output
__global__ __launch_bounds__(256) void k_fft_zy_inv(const float2* __restrict__ cin,
                                                    float* __restrict__ pos,
                                                    const void* __restrict__ xtraw, size_t xoff,
                                                    float* __restrict__ lsum,
                                                    const int* __restrict__ flag,
                                                    void* __restrict__ outp, size_t ooff) {
  __shared__ float2 P[64*66];
  __shared__ float2 tw[64];
  __shared__ float red[256];
  int t = threadIdx.x;
  if (t < 64) { float s, c; __sincosf(-(PI2/64.f)*(float)t, &s, &c); tw[t] = make_float2(c, s); }
  size_t pb = (size_t)blockIdx.x * 4096;
  const float4* src = (const float4*)(cin + pb);
  #pragma unroll
  for (int i = 0; i < 8; ++i) {
    float4 v = src[t + 256*i];
    int idx2 = (t + 256*i) * 2;
    P[(idx2 >> 6)*66 + (idx2 & 63)]     = make_float2(v.x, v.y);
    P[(idx2 >> 6)*66 + (idx2 & 63) + 1] = make_float2(v.z, v.w);
  }
  __syncthreads();
  dft64<true>(P, tw, 1, 66);
  dft64<true>(P, tw, 66, 1);
  float* pdst = pos + pb;
  int bf = *flag;
  float lacc = 0.f;
  #pragma unroll
  for (int i = 0; i < 16; ++i) {
    int idx = t + 256*i;
    float np = pdst[idx] + P[(idx >> 6)*66 + (idx & 63)].x * (1.0f/(float)VOL);
    pdst[idx] = np;
    if (outp) {
      if (bf) ((u16*)outp)[ooff + pb + idx] = f2b(np);
      else    ((float*)outp)[ooff + pb + idx] = np;
    }
    float xt = bf ? b2f(((const u16*)xtraw)[xoff + pb + idx])
                  : ((const float*)xtraw)[xoff + pb + idx];
    float d = xt - np;
    lacc = fmaf(d, d, lacc);
  }
  red[t] = lacc; __syncthreads();
  for (int s = 128; s > 0; s >>= 1) { if (t < s) red[t] += red[t+s]; __syncthreads(); }
  if (t == 0) atomicAdd(lsum, red[0]);
}

// ================= conv path (xyz-halo 66^3 layout) =================
// MFMA cellin: A = Wfi (co<8 live), K=16 packs 8 taps x 2 ch; 4 MFMAs cover 27 taps
__global__ __launch_bounds__(512, 8) void k_cellin(const float* __restrict__ pos,
                                                   const float* __restrict__ delta,
                                                   const u16* __restrict__ Wfi,
                                                   const float* __restrict__ binf,
                                                   u16* __restrict__ ci) {
  __shared__ u16 wfl[2048];           // 4096 B
  int t = threadIdx.x;
  if (t < 256) ((uint4*)wfl)[t] = ((const uint4*)Wfi)[t];
  int wv = t >> 6, l = t & 63, ln = l & 31, hi = l >> 5;
  int bid = blockIdx.x;
  int x = bid & 63, yq = (bid >> 6) & 15, b = bid >> 10;
  int y = yq * 4 + (wv >> 1), z0 = (wv & 1) * 32;
  int z = z0 + ln;
  const u16* wbase = wfl + hi * 256 + ln * 8;
  __syncthreads();
  f32x16 acc;
  #pragma unroll
  for (int r = 0; r < 16; ++r) acc[r] = 0.f;
  #pragma unroll
  for (int m = 0; m < 4; ++m) {
    unsigned pk[4];
    #pragma unroll
    for (int kk = 0; kk < 4; ++kk) {
      const int tap = m * 8 + hi * 4 + kk;
      float pv = 0.f, dv = 0.f;
      if (tap < 27) {
        const int dx = tap / 9 - 1, dy = (tap / 3) % 3 - 1, dz = tap % 3 - 1;
        int nx = x + dx, ny = y + dy, nz = z + dz;
        if ((unsigned)nx < 64u && (unsigned)ny < 64u && (unsigned)nz < 64u) {
          size_t n = (((size_t)b * 64 + nx) * 64 + ny) * 64 + nz;
          pv = pos[n]; dv = delta[n];
        }
      }
      pk[kk] = (unsigned)f2b(pv) | ((unsigned)f2b(dv) << 16);
    }
    uint4 q = make_uint4(pk[0], pk[1], pk[2], pk[3]);
    bf16x8 bfr = __builtin_bit_cast(bf16x8, q);
    bf16x8 wfr = __builtin_bit_cast(bf16x8, *(const uint4*)(wbase + m * 512));
    acc = __builtin_amdgcn_mfma_f32_32x32x16_bf16(wfr, bfr, acc, 0, 0, 0);
  }
  // D[co][voxel]: lane (ln,hi) -> voxel ln, co = q + 4*hi for acc[q], q=0..3
  size_t cslot = (size_t)b * HS + (size_t)(x + 1) * SX + (y + 1) * 66 + z + 1;
  u16 hh[4];
  #pragma unroll
  for (int q = 0; q < 4; ++q) hh[q] = f2b(acc[q] + binf[hi * 4 + q]);
  *(uint2*)(ci + cslot * 8 + hi * 4) = *(uint2*)hh;
}

// MFMA ConvLSTM: W as A / act as B, dual accumulators to break dep chain
__global__ __launch_bounds__(512, 8) void k_clstm(const u16* __restrict__ ci,
                                                  const u16* __restrict__ hC,
                                                  u16* __restrict__ hN,
                                                  u16* __restrict__ c3u,
                                                  const u16* __restrict__ Wf,
                                                  const float* __restrict__ b3f) {
  __shared__ u16 wfl[13824];          // 27648 B
  int t = threadIdx.x;
  for (int i = t; i < 1728; i += 512) ((uint4*)wfl)[i] = ((const uint4*)Wf)[i];
  int wv = t >> 6, l = t & 63, ln = l & 31, hi = l >> 5;
  int bid = blockIdx.x;
  int x = bid & 63, yq = (bid >> 6) & 15, b = bid >> 10;
  int y = yq * 4 + (wv >> 1), z0 = (wv & 1) * 32;
  size_t cslot = (size_t)b * HS + (size_t)(x + 1) * SX + (y + 1) * 66 + z0 + ln + 1;
  const u16* abase = (hi ? hC : ci) + cslot * 8;
  const u16* axm = abase - SX * 8;
  const u16* axp = abase + SX * 8;
  const u16* wbase = wfl + hi * 256 + ln * 8;
  __syncthreads();
  f32x16 acc0, acc1;
  #pragma unroll
  for (int r = 0; r < 16; ++r) { acc0[r] = 0.f; acc1[r] = 0.f; }
  #pragma unroll
  for (int tap = 0; tap < 27; ++tap) {
    const int dx = tap / 9, dy = (tap / 3) % 3 - 1, dz = tap % 3 - 1;
    const u16* ab = (dx == 0) ? axm : ((dx == 1) ? abase : axp);
    bf16x8 wfr = __builtin_bit_cast(bf16x8, *(const uint4*)(wbase + tap * 512));
    bf16x8 afr = __builtin_bit_cast(bf16x8, *(const uint4*)(ab + (dy * 66 + dz) * 8));
    if (tap & 1) acc1 = __builtin_amdgcn_mfma_f32_32x32x16_bf16(wfr, afr, acc1, 0, 0, 0);
    else         acc0 = __builtin_amdgcn_mfma_f32_32x32x16_bf16(wfr, afr, acc0, 0, 0, 0);
  }
  f32x16 acc;
  #pragma unroll
  for (int r = 0; r < 16; ++r) acc[r] = acc0[r] + acc1[r];
  float4 bi  = *(const float4*)(b3f + 4 * hi);
  float4 bff = *(const float4*)(b3f + 8 + 4 * hi);
  float4 bg  = *(const float4*)(b3f + 16 + 4 * hi);
  float4 bo_ = *(const float4*)(b3f + 24 + 4 * hi);
  const float* bip = (const float*)&bi;
  const float* bfp = (const float*)&bff;
  const float* bgp = (const float*)&bg;
  const float* bop = (const float*)&bo_;
  uint2 cu = *(const uint2*)(c3u + cslot * 8 + hi * 4);
  const u16* cp = (const u16*)&cu;
  u16 cw[4], hw[4];
  #pragma unroll
  for (int q = 0; q < 4; ++q) {
    float zi  = acc[q]      + bip[q];
    float zf  = acc[4 + q]  + bfp[q];
    float zg  = acc[8 + q]  + bgp[q];
    float zo_ = acc[12 + q] + bop[q];
    float cn = fsig(zf) * b2f(cp[q]) + fsig(zi) * ftanh(zg);
    cw[q] = f2b(cn);
    hw[q] = f2b(fsig(zo_) * ftanh(cn));
  }
  *(uint2*)(c3u + cslot * 8 + hi * 4) = *(uint2*)cw;
  *(uint2*)(hN + cslot * 8 + hi * 4)  = *(uint2*)hw;
}

// MFMA wout: A = Wfo (only co=0 nonzero), dual accumulators
__global__ __launch_bounds__(512, 8) void k_wout(const u16* __restrict__ h,
                                                 const u16* __restrict__ Wfo,
                                                 const float* __restrict__ bo,
                                                 float* __restrict__ dpw) {
  __shared__ u16 wfl[7168];           // 14336 B
  int t = threadIdx.x;
  for (int i = t; i < 896; i += 512) ((uint4*)wfl)[i] = ((const uint4*)Wfo)[i];
  int wv = t >> 6, l = t & 63, ln = l & 31, hi = l >> 5;
  int bid = blockIdx.x;
  int x = bid & 63, yq = (bid >> 6) & 15, b = bid >> 10;
  int y = yq * 4 + (wv >> 1), z0 = (wv & 1) * 32;
  size_t cslot = (size_t)b * HS + (size_t)(x + 1) * SX + (y + 1) * 66 + z0 + ln + 1;
  const u16* abase = h + cslot * 8;
  const u16* wbase = wfl + hi * 256 + ln * 8;
  __syncthreads();
  f32x16 acc0, acc1;
  #pragma unroll
  for (int r = 0; r < 16; ++r) { acc0[r] = 0.f; acc1[r] = 0.f; }
  #pragma unroll
  for (int p = 0; p < 14; ++p) {
    const int t0 = 2 * p;
    const int t1 = (2 * p + 1 < 27) ? (2 * p + 1) : 26;
    const int o0 = (t0 / 9) * SX + ((t0 / 3) % 3) * 66 + (t0 % 3) - (SX + 66 + 1);
    const int o1 = (t1 / 9) * SX + ((t1 / 3) % 3) * 66 + (t1 % 3) - (SX + 66 + 1);
    int off = hi ? o1 : o0;
    bf16x8 wfr = __builtin_bit_cast(bf16x8, *(const uint4*)(wbase + p * 512));
    bf16x8 afr = __builtin_bit_cast(bf16x8, *(const uint4*)(abase + (ptrdiff_t)off * 8));
    if (p & 1) acc1 = __builtin_amdgcn_mfma_f32_32x32x16_bf16(wfr, afr, acc1, 0, 0, 0);
    else       acc0 = __builtin_amdgcn_mfma_f32_32x32x16_bf16(wfr, afr, acc0, 0, 0, 0);
  }
  if (hi == 0) {
    size_t vox = (((size_t)b * 64 + x) * 64 + y) * 64 + z0 + ln;
    dpw[vox] = acc0[0] + acc1[0] + bo[0];
  }
}

// ================= small dense LSTM branch =================
__global__ __launch_bounds__(256) void k_small(const float* __restrict__ psp,
                                               const float* __restrict__ psd,
                                               const float* __restrict__ cnts,
                                               const float* __restrict__ Wd1,
                                               const float* __restrict__ bd1,
                                               const float* __restrict__ Wlx,
                                               const float* __restrict__ Wlh,
                                               const float* __restrict__ bl,
                                               const float* __restrict__ Wd2,
                                               const float* __restrict__ bd2,
                                               const float* __restrict__ Wc1,
                                               const float* __restrict__ bc1,
                                               float* __restrict__ h1, float* __restrict__ c1,
                                               float* __restrict__ psn) {
  __shared__ float lp[128], x1[128], hs[128], zz[512], lps[66];
  int t = threadIdx.x, b = blockIdx.x;
  if (t < 64) {
    lp[t]      = __log10f(fmaxf(psp[b*64 + t] / cnts[t] * 8.0e6f, 1e-30f));
    lp[64 + t] = __log10f(fmaxf(psd[b*64 + t] / cnts[t] * 8.0e6f, 1e-30f));
  }
  if (t < 128) hs[t] = h1[b*128 + t];
  __syncthreads();
  if (t < 128) {
    float a = bd1[t];
    for (int j = 0; j < 128; ++j) a = fmaf(lp[j], Wd1[j*128 + t], a);
    x1[t] = a;
  }
  __syncthreads();
  for (int k = t; k < 512; k += 256) {
    float a = bl[k];
    for (int u = 0; u < 128; ++u)
      a = fmaf(x1[u], Wlx[u*512 + k], fmaf(hs[u], Wlh[u*512 + k], a));
    zz[k] = a;
  }
  __syncthreads();
  if (t < 128) {
    float cv = fsig(zz[128 + t]) * c1[b*128 + t] + fsig(zz[t]) * ftanh(zz[256 + t]);
    c1[b*128 + t] = cv;
    float hv = fsig(zz[384 + t]) * ftanh(cv);
    h1[b*128 + t] = hv; hs[t] = hv;
  }
  __syncthreads();
  if (t < 64) {
    float a = bd2[t];
    for (int u = 0; u < 128; ++u) a = fmaf(hs[u], Wd2[u*64 + t], a);
    lps[t + 1] = a;
  }
  __syncthreads();
  if (t < 64) {
    float a = fmaf(Wc1[1], lps[t + 1], bc1[0]);
    if (t > 0)  a = fmaf(Wc1[0], lps[t], a);
    if (t < 63) a = fmaf(Wc1[2], lps[t + 2], a);
    psn[b*64 + t] = __expf(a);
  }
}

__global__ void k_loss(const float* __restrict__ lsum, void* __restrict__ outp,
                       const int* __restrict__ flag) {
  float l = lsum[0] * (1.0f / (float)TOT);
  if (*flag) ((u16*)outp)[TOT] = f2b(l);
  else       ((float*)outp)[TOT] = l;
}

__global__ void k_sent(u16* __restrict__ outp) { outp[0] = f2b(1000.0f); }

extern "C" void kernel_launch(void* const* d_in, const int* in_sizes, int n_in,
                              void* d_out, int out_size, void* d_ws, size_t ws_size,
                              hipStream_t stream) {
  const void* x_init = d_in[0];
  const void* y      = d_in[1];
  const void* x_true = d_in[2];
  const int*  kbin   = (const int*)d_in[3];

  int nbs = 0;
  for (int cand = 8; cand >= 1; cand >>= 1) {
    size_t n1c = (size_t)cand * VOL;
    size_t slc = (size_t)cand * HS;
    size_t need = 4 * n1c * 4            // pos,m,v,dpw f32
                + 4 * slc * 16           // c3u,ci,hA,hB (8 u16 per slot)
                + n1c * 8                // cb float2
                + (171008 + 6912 + 3584 + 1024 + (size_t)cand * (192 + 256) + 96) * 4;
    if (need <= ws_size) { nbs = cand; break; }
  }
  if (nbs == 0) { k_sent<<<1, 1, 0, stream>>>((u16*)d_out); return; }

  size_t n1 = (size_t)nbs * VOL;
  size_t sl = (size_t)nbs * HS;
  float* ws   = (float*)d_ws;
  float* pos  = ws;
  float* m    = pos + n1;
  float* v    = m + n1;
  float* dpw  = v + n1;
  u16*  c3u   = (u16*)(dpw + n1);     // sl*8 u16 each
  u16*  ci    = c3u + sl*8;
  u16*  hA    = ci + sl*8;
  u16*  hB    = hA + sl*8;
  float2* cb  = (float2*)(hB + sl*8); // n1 float2
  float* wbuf = (float*)((float*)cb + n1*2);  // 171008 f32
  u16*  Wf    = (u16*)(wbuf + 171008);        // 13824 u16 (6912 f32)
  u16*  Wfo   = Wf + 13824;                   // 7168 u16 (3584 f32)
  u16*  Wfi   = Wfo + 7168;                   // 2048 u16 (1024 f32)
  float* psp  = wbuf + 171008 + 6912 + 3584 + 1024;
  float* psd  = psp + (size_t)nbs*64;
  float* psn  = psd + (size_t)nbs*64;
  float* cnts = psn + (size_t)nbs*64;
  float* lsum = cnts + 64;            // 8
  float* h1   = lsum + 8;
  float* c1   = h1 + (size_t)nbs*128;
  int*   flag = (int*)(c1 + (size_t)nbs*128);

  float* bin_f = wbuf + 432;
  float* b3_f  = wbuf + 14264;
  float* bo_f  = wbuf + 14512; float* Wd1_f = wbuf + 14513;
  float* bd1_f = wbuf + 30897; float* Wlx_f = wbuf + 31025;
  float* Wlh_f = wbuf + 96561; float* bl_f  = wbuf + 162097;
  float* Wd2_f = wbuf + 162609; float* bd2_f = wbuf + 170801;
  float* Wc1_f = wbuf + 170865; float* bc1_f = wbuf + 170868;

  const int CB = (int)(n1 / 256);

  k_sniff<<<1, 256, 0, stream>>>((const u16*)x_init, flag);
  k_cvtall<<<(WTOT + 255) / 256, 256, 0, stream>>>(
      d_in[4], d_in[5], d_in[6], d_in[7], d_in[8], d_in[9], d_in[10], d_in[11],
      d_in[12], d_in[13], d_in[14], d_in[15], d_in[16], d_in[17], d_in[18], d_in[19],
      wbuf, flag);
  k_mkwf<<<54, 256, 0, stream>>>(d_in[6], d_in[7], flag, Wf);
  k_mkwfo<<<28, 256, 0, stream>>>(d_in[9], flag, Wfo);
  k_mkwfi<<<8, 256, 0, stream>>>(d_in[4], flag, Wfi);
  hipMemsetAsync(cnts, 0, 72 * 4, stream);      // cnts + lsum
  k_counts<<<VOL / 256, 256, 0, stream>>>(kbin, cnts);

  for (int b0 = 0; b0 < NB; b0 += nbs) {
    hipMemsetAsync(c3u, 0, sl * 64, stream);    // c3u,ci,hA,hB contiguous (halos stay 0)
    hipMemsetAsync(h1, 0, (size_t)nbs * 256 * 4, stream);
    k_cvt<<<CB, 256, 0, stream>>>(x_init, (size_t)b0 * VOL, pos, flag);

    u16* hC = hA;
    u16* hN = hB;
    for (int t = 1; t <= 4; ++t) {
      float ib1 = (float)(1.0 / (1.0 - pow(0.9, (double)t)));
      float ib2 = (float)(1.0 / (1.0 - pow(0.999, (double)t)));

      k_fft_zy_adam<<<nbs * 64, 256, 0, stream>>>(pos, y, (size_t)b0 * VOL, m, v, dpw,
                                                  cb, ib1, ib2, t == 1, flag, psp, psd);
      k_fft_x_pow<<<nbs * 64, 256, 0, stream>>>(cb, kbin, psp);
      k_fft_zy<<<nbs * 64, 256, 0, stream>>>(dpw, cb);
      k_fft_x_pow<<<nbs * 64, 256, 0, stream>>>(cb, kbin, psd);

      k_cellin<<<nbs * 1024, 512, 0, stream>>>(pos, dpw, Wfi, bin_f, ci);
      k_clstm<<<nbs * 1024, 512, 0, stream>>>(ci, hC, hN, c3u, Wf, b3_f);
      k_wout<<<nbs * 1024, 512, 0, stream>>>(hN, Wfo, bo_f, dpw);

      k_small<<<nbs, 256, 0, stream>>>(psp, psd, cnts, Wd1_f, bd1_f, Wlx_f, Wlh_f, bl_f,
                                       Wd2_f, bd2_f, Wc1_f, bc1_f, h1, c1, psn);

      k_fft_zy<<<nbs * 64, 256, 0, stream>>>(dpw, cb);
      k_fft_x_filt<<<nbs * 64, 256, 0, stream>>>(cb, kbin, psn);
      k_fft_zy_inv<<<nbs * 64, 256, 0, stream>>>(cb, pos, x_true, (size_t)b0 * VOL, lsum,
                                                 flag, (t == 4) ? d_out : nullptr,
                                                 (size_t)b0 * VOL);

      u16* tmp = hC; hC = hN; hN = tmp;
    }
  }
  k_loss<<<1, 1, 0, stream>>>(lsum, d_out, flag);
}

// Round 13
// 1279.495 us; speedup vs baseline: 1.0256x; 1.0256x over previous
//
#include <hip/hip_runtime.h>
#include <math.h>

#define NCC 64
#define NB 8
#define VOL (NCC*NCC*NCC)      // 262144 = 2^18
#define TOT (NB*VOL)           // 2097152
#define WTOT 170869            // total weight elements
#define PI2 6.2831853071795864769f
#define HS 287496              // 66*66*66 halo slots per batch elem
#define SX 4356                // 66*66

typedef unsigned short u16;
typedef __bf16 bf16x8 __attribute__((ext_vector_type(8)));
typedef float f32x16 __attribute__((ext_vector_type(16)));

__device__ __forceinline__ float b2f(u16 h){ return __uint_as_float(((unsigned)h)<<16); }
__device__ __forceinline__ u16 f2b(float f){
  unsigned u = __float_as_uint(f);
  unsigned r = (u + 0x7FFFu + ((u>>16)&1u)) >> 16;
  return (u16)r;
}
__device__ __forceinline__ float fsig(float x){ return 1.f / (1.f + __expf(-x)); }
__device__ __forceinline__ float ftanh(float x){
  float e = __expf(2.f * x);
  return 1.f - 2.f / (e + 1.f);
}

// ================= radix-8 FFT machinery =================
template<bool INV>
__device__ __forceinline__ void fft8(float2* x) {
  const float C = 0.70710678118654752440f;
  float2 s0,s1,s2,s3,s4,s5,s6,s7;
  s0 = make_float2(x[0].x + x[4].x, x[0].y + x[4].y);
  s4 = make_float2(x[0].x - x[4].x, x[0].y - x[4].y);
  s1 = make_float2(x[1].x + x[5].x, x[1].y + x[5].y);
  s5 = make_float2(x[1].x - x[5].x, x[1].y - x[5].y);
  s2 = make_float2(x[2].x + x[6].x, x[2].y + x[6].y);
  s6 = make_float2(x[2].x - x[6].x, x[2].y - x[6].y);
  s3 = make_float2(x[3].x + x[7].x, x[3].y + x[7].y);
  s7 = make_float2(x[3].x - x[7].x, x[3].y - x[7].y);
  float2 n5, n6, n7;
  if (!INV) {
    n5 = make_float2(C*(s5.x + s5.y), C*(s5.y - s5.x));
    n6 = make_float2(s6.y, -s6.x);
    n7 = make_float2(C*(s7.y - s7.x), -C*(s7.x + s7.y));
  } else {
    n5 = make_float2(C*(s5.x - s5.y), C*(s5.y + s5.x));
    n6 = make_float2(-s6.y, s6.x);
    n7 = make_float2(-C*(s7.x + s7.y), C*(s7.x - s7.y));
  }
  float2 t0,t1,t2,t3,t4,t5,t6,t7,d;
  t0 = make_float2(s0.x + s2.x, s0.y + s2.y);
  t2 = make_float2(s0.x - s2.x, s0.y - s2.y);
  t1 = make_float2(s1.x + s3.x, s1.y + s3.y);
  d  = make_float2(s1.x - s3.x, s1.y - s3.y);
  t3 = INV ? make_float2(-d.y, d.x) : make_float2(d.y, -d.x);
  t4 = make_float2(s4.x + n6.x, s4.y + n6.y);
  t6 = make_float2(s4.x - n6.x, s4.y - n6.y);
  t5 = make_float2(n5.x + n7.x, n5.y + n7.y);
  d  = make_float2(n5.x - n7.x, n5.y - n7.y);
  t7 = INV ? make_float2(-d.y, d.x) : make_float2(d.y, -d.x);
  x[0] = make_float2(t0.x + t1.x, t0.y + t1.y);
  x[1] = make_float2(t0.x - t1.x, t0.y - t1.y);
  x[2] = make_float2(t2.x + t3.x, t2.y + t3.y);
  x[3] = make_float2(t2.x - t3.x, t2.y - t3.y);
  x[4] = make_float2(t4.x + t5.x, t4.y + t5.y);
  x[5] = make_float2(t4.x - t5.x, t4.y - t5.y);
  x[6] = make_float2(t6.x + t7.x, t6.y + t7.y);
  x[7] = make_float2(t6.x - t7.x, t6.y - t7.y);
}

template<bool INV>
__device__ __forceinline__ void dft64(float2* Pf, const float2* tw, int ls, int ns) {
  const int BR[8] = {0,4,2,6,1,5,3,7};
  int t = threadIdx.x;
  int L0 = t >> 3, b = t & 7, L1 = L0 + 32;
  float2 v0[8], v1[8];
  #pragma unroll
  for (int a = 0; a < 8; ++a) v0[a] = Pf[L0*ls + (8*a + b)*ns];
  #pragma unroll
  for (int a = 0; a < 8; ++a) v1[a] = Pf[L1*ls + (8*a + b)*ns];
  __syncthreads();
  fft8<INV>(v0); fft8<INV>(v1);
  #pragma unroll
  for (int r = 0; r < 8; ++r) {
    float2 w = tw[(b * r) & 63];
    if (INV) w.y = -w.y;
    float2 a0 = v0[BR[r]], a1 = v1[BR[r]];
    Pf[L0*ls + (8*b + r)*ns] = make_float2(a0.x*w.x - a0.y*w.y, a0.x*w.y + a0.y*w.x);
    Pf[L1*ls + (8*b + r)*ns] = make_float2(a1.x*w.x - a1.y*w.y, a1.x*w.y + a1.y*w.x);
  }
  __syncthreads();
  int r = t & 7;
  #pragma unroll
  for (int q = 0; q < 8; ++q) v0[q] = Pf[L0*ls + (8*q + r)*ns];
  #pragma unroll
  for (int q = 0; q < 8; ++q) v1[q] = Pf[L1*ls + (8*q + r)*ns];
  fft8<INV>(v0); fft8<INV>(v1);
  #pragma unroll
  for (int j = 0; j < 8; ++j) {
    Pf[L0*ls + (8*BR[j] + r)*ns] = v0[j];
    Pf[L1*ls + (8*BR[j] + r)*ns] = v1[j];
  }
  __syncthreads();
}

// ================= setup kernels =================
__global__ __launch_bounds__(256) void k_sniff(const u16* __restrict__ x, int* __restrict__ flag) {
  __shared__ int cnt;
  if (threadIdx.x == 0) cnt = 0;
  __syncthreads();
  int sane = 0;
  for (int i = threadIdx.x; i < 1024; i += 256) {
    u16 h = x[2 * i];
    int e = (h >> 7) & 0xFF;
    if (h == 0 || (e >= 0x68 && e <= 0x8F)) sane++;
  }
  atomicAdd(&cnt, sane);
  __syncthreads();
  if (threadIdx.x == 0) flag[0] = (cnt >= 768) ? 1 : 0;
}

__global__ __launch_bounds__(256) void k_cvt(const void* __restrict__ in, size_t eoff,
                                             float* __restrict__ out, const int* __restrict__ flag) {
  size_t i = (size_t)blockIdx.x * 256 + threadIdx.x;
  if (*flag) out[i] = b2f(((const u16*)in)[eoff + i]);
  else       out[i] = ((const float*)in)[eoff + i];
}

__global__ __launch_bounds__(256) void k_cvtall(
    const void* s0, const void* s1, const void* s2, const void* s3,
    const void* s4, const void* s5, const void* s6, const void* s7,
    const void* s8, const void* s9, const void* s10, const void* s11,
    const void* s12, const void* s13, const void* s14, const void* s15,
    float* __restrict__ out, const int* __restrict__ flag) {
  const void* ps[16] = {s0,s1,s2,s3,s4,s5,s6,s7,s8,s9,s10,s11,s12,s13,s14,s15};
  const int offs[17] = {0,432,440,7352,14264,14296,14512,14513,30897,31025,
                        96561,162097,162609,170801,170865,170868,170869};
  int i = blockIdx.x * 256 + threadIdx.x;
  if (i >= WTOT) return;
  int s = 0;
  #pragma unroll
  for (int k = 1; k < 16; ++k) if (i >= offs[k]) s = k;
  int j = i - offs[s];
  if (*flag) out[i] = b2f(((const u16*)ps[s])[j]);
  else       out[i] = ((const float*)ps[s])[j];
}

// Wf[tap][hi][co][j] : u16 idx = tap*512 + hi*256 + co*8 + j
__global__ __launch_bounds__(256) void k_mkwf(const void* __restrict__ Wx, const void* __restrict__ Wh,
                                              const int* __restrict__ flag, u16* __restrict__ Wf) {
  int i = blockIdx.x * 256 + threadIdx.x;   // 13824
  if (i >= 13824) return;
  int j = i & 7, co = (i >> 3) & 31, hi = (i >> 8) & 1, tap = i >> 9;
  int src = tap * 256 + j * 32 + co;
  const void* P = hi ? Wh : Wx;
  u16 val;
  if (*flag) val = ((const u16*)P)[src];
  else       val = f2b(((const float*)P)[src]);
  Wf[i] = val;
}

// Wfo[p][hi][co][j]: only co==0 carries Wo[tap=2p+hi][j]; rest zero
__global__ __launch_bounds__(256) void k_mkwfo(const void* __restrict__ Wo,
                                               const int* __restrict__ flag, u16* __restrict__ Wfo) {
  int i = blockIdx.x * 256 + threadIdx.x;   // 7168 = 14*512
  if (i >= 7168) return;
  int j = i & 7, co = (i >> 3) & 31, hi = (i >> 8) & 1, p = i >> 9;
  int tap = 2 * p + hi;
  u16 val = 0;
  if (co == 0 && tap < 27) {
    int src = tap * 8 + j;
    val = *flag ? ((const u16*)Wo)[src] : f2b(((const float*)Wo)[src]);
  }
  Wfo[i] = val;
}

// Wfi[m][hi][co][j]: A[row=co][k=hi*8+j] for cellin MFMA; k -> (tap = m*8 + (k>>1), ch = k&1)
__global__ __launch_bounds__(256) void k_mkwfi(const void* __restrict__ Wi,
                                               const int* __restrict__ flag, u16* __restrict__ Wfi) {
  int i = blockIdx.x * 256 + threadIdx.x;   // 2048 = 4*512
  if (i >= 2048) return;
  int j = i & 7, co = (i >> 3) & 31, hi = (i >> 8) & 1, m = i >> 9;
  int k = hi * 8 + j;
  int tap = m * 8 + (k >> 1), ch = k & 1;
  u16 val = 0;
  if (co < 8 && tap < 27) {
    int src = tap * 16 + ch * 8 + co;
    val = *flag ? ((const u16*)Wi)[src] : f2b(((const float*)Wi)[src]);
  }
  Wfi[i] = val;
}

__global__ __launch_bounds__(256) void k_counts(const int* __restrict__ kbin,
                                                float* __restrict__ cnts) {
  __shared__ float s[NCC];
  int t = threadIdx.x;
  if (t < NCC) s[t] = 0.f;
  __syncthreads();
  int i = blockIdx.x * 256 + t;
  atomicAdd(&s[kbin[i]], 1.f);
  __syncthreads();
  if (t < NCC) atomicAdd(&cnts[t], s[t]);
}

// ================= FFT kernels =================
__global__ __launch_bounds__(256) void k_fft_zy_adam(
    const float* __restrict__ pos, const void* __restrict__ yraw, size_t yoff,
    float* __restrict__ m, float* __restrict__ v, float* __restrict__ dpw,
    float2* __restrict__ cout, float ib1, float ib2, int first,
    const int* __restrict__ flag, float* __restrict__ psp, float* __restrict__ psd) {
  __shared__ float2 P[64*66];
  __shared__ float2 tw[64];
  int t = threadIdx.x;
  if (t < 64) { float s, c; __sincosf(-(PI2/64.f)*(float)t, &s, &c); tw[t] = make_float2(c, s); }
  int bb = blockIdx.x >> 6, xx = blockIdx.x & 63;
  if (xx == 0) {
    if (t < 64)                 psp[bb*64 + t] = 0.f;
    else if (t < 128)           psd[bb*64 + (t - 64)] = 0.f;
  }
  size_t pb = (size_t)blockIdx.x * 4096;
  int bf = *flag;
  #pragma unroll
  for (int i = 0; i < 4; ++i) {
    int i4 = t + 256*i;
    float4 p4 = ((const float4*)(pos + pb))[i4];
    float yv[4];
    if (bf) {
      uint2 yu = ((const uint2*)((const u16*)yraw + yoff + pb))[i4];
      const u16* yp = (const u16*)&yu;
      yv[0]=b2f(yp[0]); yv[1]=b2f(yp[1]); yv[2]=b2f(yp[2]); yv[3]=b2f(yp[3]);
    } else {
      float4 y4 = ((const float4*)((const float*)yraw + yoff + pb))[i4];
      yv[0]=y4.x; yv[1]=y4.y; yv[2]=y4.z; yv[3]=y4.w;
    }
    float pv[4] = {p4.x, p4.y, p4.z, p4.w};
    float mo[4], vo[4], dd[4];
    if (!first) {
      float4 m4 = ((const float4*)(m + pb))[i4];
      float4 v4 = ((const float4*)(v + pb))[i4];
      mo[0]=m4.x; mo[1]=m4.y; mo[2]=m4.z; mo[3]=m4.w;
      vo[0]=v4.x; vo[1]=v4.y; vo[2]=v4.z; vo[3]=v4.w;
    }
    #pragma unroll
    for (int c = 0; c < 4; ++c) {
      float g = pv[c] - yv[c];
      float mi = first ? 0.1f*g : 0.9f*mo[c] + 0.1f*g;
      float vi = first ? 0.001f*g*g : 0.999f*vo[c] + 0.001f*g*g;
      mo[c] = mi; vo[c] = vi;
      dd[c] = -0.1f * (mi * ib1) / (sqrtf(vi * ib2) + 1e-7f);
    }
    ((float4*)(m + pb))[i4]   = make_float4(mo[0], mo[1], mo[2], mo[3]);
    ((float4*)(v + pb))[i4]   = make_float4(vo[0], vo[1], vo[2], vo[3]);
    ((float4*)(dpw + pb))[i4] = make_float4(dd[0], dd[1], dd[2], dd[3]);
    int base = i4 * 4;
    float2* row = P + (base >> 6)*66 + (base & 63);
    row[0] = make_float2(pv[0], 0.f);
    row[1] = make_float2(pv[1], 0.f);
    row[2] = make_float2(pv[2], 0.f);
    row[3] = make_float2(pv[3], 0.f);
  }
  __syncthreads();
  dft64<false>(P, tw, 66, 1);
  dft64<false>(P, tw, 1, 66);
  float4* dst = (float4*)(cout + pb);
  #pragma unroll
  for (int i = 0; i < 8; ++i) {
    int idx2 = (t + 256*i) * 2;
    float2 a = P[(idx2 >> 6)*66 + (idx2 & 63)];
    float2 b = P[(idx2 >> 6)*66 + (idx2 & 63) + 1];
    dst[t + 256*i] = make_float4(a.x, a.y, b.x, b.y);
  }
}

__global__ __launch_bounds__(256) void k_fft_zy(const float* __restrict__ rin,
                                                float2* __restrict__ cout) {
  __shared__ float2 P[64*66];
  __shared__ float2 tw[64];
  int t = threadIdx.x;
  if (t < 64) { float s, c; __sincosf(-(PI2/64.f)*(float)t, &s, &c); tw[t] = make_float2(c, s); }
  const float* src = rin + (size_t)blockIdx.x * 4096;
  #pragma unroll
  for (int i = 0; i < 4; ++i) {
    float4 v = ((const float4*)src)[t + 256*i];
    int base = (t + 256*i) * 4;
    float2* row = P + (base >> 6)*66 + (base & 63);
    row[0] = make_float2(v.x, 0.f);
    row[1] = make_float2(v.y, 0.f);
    row[2] = make_float2(v.z, 0.f);
    row[3] = make_float2(v.w, 0.f);
  }
  __syncthreads();
  dft64<false>(P, tw, 66, 1);
  dft64<false>(P, tw, 1, 66);
  float4* dst = (float4*)(cout + (size_t)blockIdx.x * 4096);
  #pragma unroll
  for (int i = 0; i < 8; ++i) {
    int idx2 = (t + 256*i) * 2;
    float2 a = P[(idx2 >> 6)*66 + (idx2 & 63)];
    float2 b = P[(idx2 >> 6)*66 + (idx2 & 63) + 1];
    dst[t + 256*i] = make_float4(a.x, a.y, b.x, b.y);
  }
}

__global__ __launch_bounds__(256) void k_fft_x_pow(const float2* __restrict__ cin,
                                                   const int* __restrict__ kb,
                                                   float* __restrict__ psum) {
  __shared__ float2 P[64*66];
  __shared__ float2 tw[64];
  __shared__ float pb[64];
  int t = threadIdx.x;
  if (t < 64) { float s, c; __sincosf(-(PI2/64.f)*(float)t, &s, &c); tw[t] = make_float2(c, s); pb[t] = 0.f; }
  int b = blockIdx.x >> 6, y = blockIdx.x & 63;
  #pragma unroll
  for (int i = 0; i < 8; ++i) {
    int idx2 = (t + 256*i) * 2;
    int x = idx2 >> 6, z = idx2 & 63;
    float4 v = *(const float4*)(cin + (((size_t)(b*64 + x)*64 + y)*64 + z));
    P[x*66 + z]     = make_float2(v.x, v.y);
    P[x*66 + z + 1] = make_float2(v.z, v.w);
  }
  __syncthreads();
  dft64<false>(P, tw, 1, 66);
  const float INV2 = 1.0f / ((float)VOL * (float)VOL);
  #pragma unroll
  for (int i = 0; i < 16; ++i) {
    int idx = t + 256*i;
    int x = idx >> 6, z = idx & 63;
    float2 a = P[x*66 + z];
    float pm = (a.x*a.x + a.y*a.y) * INV2;
    atomicAdd(&pb[kb[(x*64 + y)*64 + z]], pm);
  }
  __syncthreads();
  if (t < 64) atomicAdd(&psum[b*64 + t], pb[t]);
}

__global__ __launch_bounds__(256) void k_fft_x_filt(float2* __restrict__ cb,
                                                    const int* __restrict__ kb,
                                                    const float* __restrict__ psn) {
  __shared__ float2 P[64*66];
  __shared__ float2 tw[64];
  int t = threadIdx.x;
  if (t < 64) { float s, c; __sincosf(-(PI2/64.f)*(float)t, &s, &c); tw[t] = make_float2(c, s); }
  int b = blockIdx.x >> 6, y = blockIdx.x & 63;
  #pragma unroll
  for (int i = 0; i < 8; ++i) {
    int idx2 = (t + 256*i) * 2;
    int x = idx2 >> 6, z = idx2 & 63;
    float4 v = *(const float4*)(cb + (((size_t)(b*64 + x)*64 + y)*64 + z));
    P[x*66 + z]     = make_float2(v.x, v.y);
    P[x*66 + z + 1] = make_float2(v.z, v.w);
  }
  __syncthreads();
  dft64<false>(P, tw, 1, 66);
  #pragma unroll
  for (int i = 0; i < 16; ++i) {
    int idx = t + 256*i;
    int x = idx >> 6, z = idx & 63;
    float fac = sqrtf(psn[b*64 + kb[(x*64 + y)*64 + z]]);
    float2 a = P[x*66 + z];
    P[x*66 + z] = make_float2(a.x * fac, a.y * fac);
  }
  __syncthreads();
  dft64<true>(P, tw, 1, 66);
  #pragma unroll
  for (int i = 0; i < 8; ++i) {
    int idx2 = (t + 256*i) * 2;
    int x = idx2 >> 6, z = idx2 & 63;
    float2 a = P[x*66 + z], c = P[x*66 + z + 1];
    *(float4*)(cb + (((size_t)(b*64 + x)*64 + y)*64 + z)) = make_float4(a.x, a.y, c.x, c.y);
  }
}

// inverse y,z + pos update + loss; optionally writes final output
__global__ __launch_bounds__(256) void k_fft_zy_inv(const float2* __restrict__ cin,
                                                    float* __restrict__ pos,
                                                    const void* __restrict__ xtraw, size_t xoff,
                                                    float* __restrict__ lsum,
                                                    const int* __restrict__ flag,
                                                    void* __restrict__ outp, size_t ooff) {
  __shared__ float2 P[64*66];
  __shared__ float2 tw[64];
  __shared__ float red[256];
  int t = threadIdx.x;
  if (t < 64) { float s, c; __sincosf(-(PI2/64.f)*(float)t, &s, &c); tw[t] = make_float2(c, s); }
  size_t pb = (size_t)blockIdx.x * 4096;
  const float4* src = (const float4*)(cin + pb);
  #pragma unroll
  for (int i = 0; i < 8; ++i) {
    float4 v = src[t + 256*i];
    int idx2 = (t + 256*i) * 2;
    P[(idx2 >> 6)*66 + (idx2 & 63)]     = make_float2(v.x, v.y);
    P[(idx2 >> 6)*66 + (idx2 & 63) + 1] = make_float2(v.z, v.w);
  }
  __syncthreads();
  dft64<true>(P, tw, 1, 66);
  dft64<true>(P, tw, 66, 1);
  float* pdst = pos + pb;
  int bf = *flag;
  float lacc = 0.f;
  #pragma unroll
  for (int i = 0; i < 16; ++i) {
    int idx = t + 256*i;
    float np = pdst[idx] + P[(idx >> 6)*66 + (idx & 63)].x * (1.0f/(float)VOL);
    pdst[idx] = np;
    if (outp) {
      if (bf) ((u16*)outp)[ooff + pb + idx] = f2b(np);
      else    ((float*)outp)[ooff + pb + idx] = np;
    }
    float xt = bf ? b2f(((const u16*)xtraw)[xoff + pb + idx])
                  : ((const float*)xtraw)[xoff + pb + idx];
    float d = xt - np;
    lacc = fmaf(d, d, lacc);
  }
  red[t] = lacc; __syncthreads();
  for (int s = 128; s > 0; s >>= 1) { if (t < s) red[t] += red[t+s]; __syncthreads(); }
  if (t == 0) atomicAdd(lsum, red[0]);
}

// ================= conv path (xyz-halo 66^3 layout) =================
// MFMA cellin: A = Wfi (co<8 live), K=16 packs 8 taps x 2 ch; 4 MFMAs cover 27 taps
__global__ __launch_bounds__(512, 8) void k_cellin(const float* __restrict__ pos,
                                                   const float* __restrict__ delta,
                                                   const u16* __restrict__ Wfi,
                                                   const float* __restrict__ binf,
                                                   u16* __restrict__ ci) {
  __shared__ u16 wfl[2048];           // 4096 B
  int t = threadIdx.x;
  if (t < 256) ((uint4*)wfl)[t] = ((const uint4*)Wfi)[t];
  int wv = t >> 6, l = t & 63, ln = l & 31, hi = l >> 5;
  int bid = blockIdx.x;
  int x = bid & 63, yq = (bid >> 6) & 15, b = bid >> 10;
  int y = yq * 4 + (wv >> 1), z0 = (wv & 1) * 32;
  int z = z0 + ln;
  const u16* wbase = wfl + hi * 256 + ln * 8;
  __syncthreads();
  f32x16 acc;
  #pragma unroll
  for (int r = 0; r < 16; ++r) acc[r] = 0.f;
  #pragma unroll
  for (int m = 0; m < 4; ++m) {
    unsigned pk[4];
    #pragma unroll
    for (int kk = 0; kk < 4; ++kk) {
      const int tap = m * 8 + hi * 4 + kk;
      float pv = 0.f, dv = 0.f;
      if (tap < 27) {
        const int dx = tap / 9 - 1, dy = (tap / 3) % 3 - 1, dz = tap % 3 - 1;
        int nx = x + dx, ny = y + dy, nz = z + dz;
        if ((unsigned)nx < 64u && (unsigned)ny < 64u && (unsigned)nz < 64u) {
          size_t n = (((size_t)b * 64 + nx) * 64 + ny) * 64 + nz;
          pv = pos[n]; dv = delta[n];
        }
      }
      pk[kk] = (unsigned)f2b(pv) | ((unsigned)f2b(dv) << 16);
    }
    uint4 q = make_uint4(pk[0], pk[1], pk[2], pk[3]);
    bf16x8 bfr = __builtin_bit_cast(bf16x8, q);
    bf16x8 wfr = __builtin_bit_cast(bf16x8, *(const uint4*)(wbase + m * 512));
    acc = __builtin_amdgcn_mfma_f32_32x32x16_bf16(wfr, bfr, acc, 0, 0, 0);
  }
  size_t cslot = (size_t)b * HS + (size_t)(x + 1) * SX + (y + 1) * 66 + z + 1;
  u16 hh[4];
  #pragma unroll
  for (int q = 0; q < 4; ++q) hh[q] = f2b(acc[q] + binf[hi * 4 + q]);
  *(uint2*)(ci + cslot * 8 + hi * 4) = *(uint2*)hh;
}

// MFMA ConvLSTM: W as A / act as B, xyz-halo -> 27 unconditional taps (single acc)
__global__ __launch_bounds__(512, 8) void k_clstm(const u16* __restrict__ ci,
                                                  const u16* __restrict__ hC,
                                                  u16* __restrict__ hN,
                                                  u16* __restrict__ c3u,
                                                  const u16* __restrict__ Wf,
                                                  const float* __restrict__ b3f) {
  __shared__ u16 wfl[13824];          // 27648 B (only LDS)
  int t = threadIdx.x;
  for (int i = t; i < 1728; i += 512) ((uint4*)wfl)[i] = ((const uint4*)Wf)[i];
  int wv = t >> 6, l = t & 63, ln = l & 31, hi = l >> 5;
  int bid = blockIdx.x;
  int x = bid & 63, yq = (bid >> 6) & 15, b = bid >> 10;
  int y = yq * 4 + (wv >> 1), z0 = (wv & 1) * 32;
  size_t cslot = (size_t)b * HS + (size_t)(x + 1) * SX + (y + 1) * 66 + z0 + ln + 1;
  const u16* abase = (hi ? hC : ci) + cslot * 8;
  const u16* axm = abase - SX * 8;
  const u16* axp = abase + SX * 8;
  const u16* wbase = wfl + hi * 256 + ln * 8;
  __syncthreads();
  f32x16 acc;
  #pragma unroll
  for (int r = 0; r < 16; ++r) acc[r] = 0.f;
  #pragma unroll
  for (int tap = 0; tap < 27; ++tap) {
    const int dx = tap / 9, dy = (tap / 3) % 3 - 1, dz = tap % 3 - 1;
    const u16* ab = (dx == 0) ? axm : ((dx == 1) ? abase : axp);
    bf16x8 wfr = __builtin_bit_cast(bf16x8, *(const uint4*)(wbase + tap * 512));
    bf16x8 afr = __builtin_bit_cast(bf16x8, *(const uint4*)(ab + (dy * 66 + dz) * 8));
    acc = __builtin_amdgcn_mfma_f32_32x32x16_bf16(wfr, afr, acc, 0, 0, 0);
  }
  float4 bi  = *(const float4*)(b3f + 4 * hi);
  float4 bff = *(const float4*)(b3f + 8 + 4 * hi);
  float4 bg  = *(const float4*)(b3f + 16 + 4 * hi);
  float4 bo_ = *(const float4*)(b3f + 24 + 4 * hi);
  const float* bip = (const float*)&bi;
  const float* bfp = (const float*)&bff;
  const float* bgp = (const float*)&bg;
  const float* bop = (const float*)&bo_;
  uint2 cu = *(const uint2*)(c3u + cslot * 8 + hi * 4);
  const u16* cp = (const u16*)&cu;
  u16 cw[4], hw[4];
  #pragma unroll
  for (int q = 0; q < 4; ++q) {
    float zi  = acc[q]      + bip[q];
    float zf  = acc[4 + q]  + bfp[q];
    float zg  = acc[8 + q]  + bgp[q];
    float zo_ = acc[12 + q] + bop[q];
    float cn = fsig(zf) * b2f(cp[q]) + fsig(zi) * ftanh(zg);
    cw[q] = f2b(cn);
    hw[q] = f2b(fsig(zo_) * ftanh(cn));
  }
  *(uint2*)(c3u + cslot * 8 + hi * 4) = *(uint2*)cw;
  *(uint2*)(hN + cslot * 8 + hi * 4)  = *(uint2*)hw;
}

// MFMA wout: A = Wfo (only co=0 nonzero), K=16 packs two taps (hi = tap parity), single acc
__global__ __launch_bounds__(512, 8) void k_wout(const u16* __restrict__ h,
                                                 const u16* __restrict__ Wfo,
                                                 const float* __restrict__ bo,
                                                 float* __restrict__ dpw) {
  __shared__ u16 wfl[7168];           // 14336 B
  int t = threadIdx.x;
  for (int i = t; i < 896; i += 512) ((uint4*)wfl)[i] = ((const uint4*)Wfo)[i];
  int wv = t >> 6, l = t & 63, ln = l & 31, hi = l >> 5;
  int bid = blockIdx.x;
  int x = bid & 63, yq = (bid >> 6) & 15, b = bid >> 10;
  int y = yq * 4 + (wv >> 1), z0 = (wv & 1) * 32;
  size_t cslot = (size_t)b * HS + (size_t)(x + 1) * SX + (y + 1) * 66 + z0 + ln + 1;
  const u16* abase = h + cslot * 8;
  const u16* wbase = wfl + hi * 256 + ln * 8;
  __syncthreads();
  f32x16 acc;
  #pragma unroll
  for (int r = 0; r < 16; ++r) acc[r] = 0.f;
  #pragma unroll
  for (int p = 0; p < 14; ++p) {
    const int t0 = 2 * p;
    const int t1 = (2 * p + 1 < 27) ? (2 * p + 1) : 26;
    const int o0 = (t0 / 9) * SX + ((t0 / 3) % 3) * 66 + (t0 % 3) - (SX + 66 + 1);
    const int o1 = (t1 / 9) * SX + ((t1 / 3) % 3) * 66 + (t1 % 3) - (SX + 66 + 1);
    int off = hi ? o1 : o0;
    bf16x8 wfr = __builtin_bit_cast(bf16x8, *(const uint4*)(wbase + p * 512));
    bf16x8 afr = __builtin_bit_cast(bf16x8, *(const uint4*)(abase + (ptrdiff_t)off * 8));
    acc = __builtin_amdgcn_mfma_f32_32x32x16_bf16(wfr, afr, acc, 0, 0, 0);
  }
  if (hi == 0) {
    size_t vox = (((size_t)b * 64 + x) * 64 + y) * 64 + z0 + ln;
    dpw[vox] = acc[0] + bo[0];
  }
}

// ================= small dense LSTM branch =================
__global__ __launch_bounds__(256) void k_small(const float* __restrict__ psp,
                                               const float* __restrict__ psd,
                                               const float* __restrict__ cnts,
                                               const float* __restrict__ Wd1,
                                               const float* __restrict__ bd1,
                                               const float* __restrict__ Wlx,
                                               const float* __restrict__ Wlh,
                                               const float* __restrict__ bl,
                                               const float* __restrict__ Wd2,
                                               const float* __restrict__ bd2,
                                               const float* __restrict__ Wc1,
                                               const float* __restrict__ bc1,
                                               float* __restrict__ h1, float* __restrict__ c1,
                                               float* __restrict__ psn) {
  __shared__ float lp[128], x1[128], hs[128], zz[512], lps[66];
  int t = threadIdx.x, b = blockIdx.x;
  if (t < 64) {
    lp[t]      = __log10f(fmaxf(psp[b*64 + t] / cnts[t] * 8.0e6f, 1e-30f));
    lp[64 + t] = __log10f(fmaxf(psd[b*64 + t] / cnts[t] * 8.0e6f, 1e-30f));
  }
  if (t < 128) hs[t] = h1[b*128 + t];
  __syncthreads();
  if (t < 128) {
    float a = bd1[t];
    for (int j = 0; j < 128; ++j) a = fmaf(lp[j], Wd1[j*128 + t], a);
    x1[t] = a;
  }
  __syncthreads();
  for (int k = t; k < 512; k += 256) {
    float a = bl[k];
    for (int u = 0; u < 128; ++u)
      a = fmaf(x1[u], Wlx[u*512 + k], fmaf(hs[u], Wlh[u*512 + k], a));
    zz[k] = a;
  }
  __syncthreads();
  if (t < 128) {
    float cv = fsig(zz[128 + t]) * c1[b*128 + t] + fsig(zz[t]) * ftanh(zz[256 + t]);
    c1[b*128 + t] = cv;
    float hv = fsig(zz[384 + t]) * ftanh(cv);
    h1[b*128 + t] = hv; hs[t] = hv;
  }
  __syncthreads();
  if (t < 64) {
    float a = bd2[t];
    for (int u = 0; u < 128; ++u) a = fmaf(hs[u], Wd2[u*64 + t], a);
    lps[t + 1] = a;
  }
  __syncthreads();
  if (t < 64) {
    float a = fmaf(Wc1[1], lps[t + 1], bc1[0]);
    if (t > 0)  a = fmaf(Wc1[0], lps[t], a);
    if (t < 63) a = fmaf(Wc1[2], lps[t + 2], a);
    psn[b*64 + t] = __expf(a);
  }
}

__global__ void k_loss(const float* __restrict__ lsum, void* __restrict__ outp,
                       const int* __restrict__ flag) {
  float l = lsum[0] * (1.0f / (float)TOT);
  if (*flag) ((u16*)outp)[TOT] = f2b(l);
  else       ((float*)outp)[TOT] = l;
}

__global__ void k_sent(u16* __restrict__ outp) { outp[0] = f2b(1000.0f); }

extern "C" void kernel_launch(void* const* d_in, const int* in_sizes, int n_in,
                              void* d_out, int out_size, void* d_ws, size_t ws_size,
                              hipStream_t stream) {
  const void* x_init = d_in[0];
  const void* y      = d_in[1];
  const void* x_true = d_in[2];
  const int*  kbin   = (const int*)d_in[3];

  int nbs = 0;
  for (int cand = 8; cand >= 1; cand >>= 1) {
    size_t n1c = (size_t)cand * VOL;
    size_t slc = (size_t)cand * HS;
    size_t need = 4 * n1c * 4            // pos,m,v,dpw f32
                + 4 * slc * 16           // c3u,ci,hA,hB (8 u16 per slot)
                + n1c * 8                // cb float2
                + (171008 + 6912 + 3584 + 1024 + (size_t)cand * (192 + 256) + 96) * 4;
    if (need <= ws_size) { nbs = cand; break; }
  }
  if (nbs == 0) { k_sent<<<1, 1, 0, stream>>>((u16*)d_out); return; }

  size_t n1 = (size_t)nbs * VOL;
  size_t sl = (size_t)nbs * HS;
  float* ws   = (float*)d_ws;
  float* pos  = ws;
  float* m    = pos + n1;
  float* v    = m + n1;
  float* dpw  = v + n1;
  u16*  c3u   = (u16*)(dpw + n1);     // sl*8 u16 each
  u16*  ci    = c3u + sl*8;
  u16*  hA    = ci + sl*8;
  u16*  hB    = hA + sl*8;
  float2* cb  = (float2*)(hB + sl*8); // n1 float2
  float* wbuf = (float*)((float*)cb + n1*2);  // 171008 f32
  u16*  Wf    = (u16*)(wbuf + 171008);        // 13824 u16 (6912 f32)
  u16*  Wfo   = Wf + 13824;                   // 7168 u16 (3584 f32)
  u16*  Wfi   = Wfo + 7168;                   // 2048 u16 (1024 f32)
  float* psp  = wbuf + 171008 + 6912 + 3584 + 1024;
  float* psd  = psp + (size_t)nbs*64;
  float* psn  = psd + (size_t)nbs*64;
  float* cnts = psn + (size_t)nbs*64;
  float* lsum = cnts + 64;            // 8
  float* h1   = lsum + 8;
  float* c1   = h1 + (size_t)nbs*128;
  int*   flag = (int*)(c1 + (size_t)nbs*128);

  float* bin_f = wbuf + 432;
  float* b3_f  = wbuf + 14264;
  float* bo_f  = wbuf + 14512; float* Wd1_f = wbuf + 14513;
  float* bd1_f = wbuf + 30897; float* Wlx_f = wbuf + 31025;
  float* Wlh_f = wbuf + 96561; float* bl_f  = wbuf + 162097;
  float* Wd2_f = wbuf + 162609; float* bd2_f = wbuf + 170801;
  float* Wc1_f = wbuf + 170865; float* bc1_f = wbuf + 170868;

  const int CB = (int)(n1 / 256);

  k_sniff<<<1, 256, 0, stream>>>((const u16*)x_init, flag);
  k_cvtall<<<(WTOT + 255) / 256, 256, 0, stream>>>(
      d_in[4], d_in[5], d_in[6], d_in[7], d_in[8], d_in[9], d_in[10], d_in[11],
      d_in[12], d_in[13], d_in[14], d_in[15], d_in[16], d_in[17], d_in[18], d_in[19],
      wbuf, flag);
  k_mkwf<<<54, 256, 0, stream>>>(d_in[6], d_in[7], flag, Wf);
  k_mkwfo<<<28, 256, 0, stream>>>(d_in[9], flag, Wfo);
  k_mkwfi<<<8, 256, 0, stream>>>(d_in[4], flag, Wfi);
  hipMemsetAsync(cnts, 0, 72 * 4, stream);      // cnts + lsum
  k_counts<<<VOL / 256, 256, 0, stream>>>(kbin, cnts);

  for (int b0 = 0; b0 < NB; b0 += nbs) {
    hipMemsetAsync(c3u, 0, sl * 64, stream);    // c3u,ci,hA,hB contiguous (halos stay 0)
    hipMemsetAsync(h1, 0, (size_t)nbs * 256 * 4, stream);
    k_cvt<<<CB, 256, 0, stream>>>(x_init, (size_t)b0 * VOL, pos, flag);

    u16* hC = hA;
    u16* hN = hB;
    for (int t = 1; t <= 4; ++t) {
      float ib1 = (float)(1.0 / (1.0 - pow(0.9, (double)t)));
      float ib2 = (float)(1.0 / (1.0 - pow(0.999, (double)t)));

      k_fft_zy_adam<<<nbs * 64, 256, 0, stream>>>(pos, y, (size_t)b0 * VOL, m, v, dpw,
                                                  cb, ib1, ib2, t == 1, flag, psp, psd);
      k_fft_x_pow<<<nbs * 64, 256, 0, stream>>>(cb, kbin, psp);
      k_fft_zy<<<nbs * 64, 256, 0, stream>>>(dpw, cb);
      k_fft_x_pow<<<nbs * 64, 256, 0, stream>>>(cb, kbin, psd);

      k_cellin<<<nbs * 1024, 512, 0, stream>>>(pos, dpw, Wfi, bin_f, ci);
      k_clstm<<<nbs * 1024, 512, 0, stream>>>(ci, hC, hN, c3u, Wf, b3_f);
      k_wout<<<nbs * 1024, 512, 0, stream>>>(hN, Wfo, bo_f, dpw);

      k_small<<<nbs, 256, 0, stream>>>(psp, psd, cnts, Wd1_f, bd1_f, Wlx_f, Wlh_f, bl_f,
                                       Wd2_f, bd2_f, Wc1_f, bc1_f, h1, c1, psn);

      k_fft_zy<<<nbs * 64, 256, 0, stream>>>(dpw, cb);
      k_fft_x_filt<<<nbs * 64, 256, 0, stream>>>(cb, kbin, psn);
      k_fft_zy_inv<<<nbs * 64, 256, 0, stream>>>(cb, pos, x_true, (size_t)b0 * VOL, lsum,
                                                 flag, (t == 4) ? d_out : nullptr,
                                                 (size_t)b0 * VOL);

      u16* tmp = hC; hC = hN; hN = tmp;
    }
  }
  k_loss<<<1, 1, 0, stream>>>(lsum, d_out, flag);
}